// Round 1
// baseline (4134.483 us; speedup 1.0000x reference)
//
#include <hip/hip_runtime.h>

#define NCLS 5
#define NQRY 75
#define NTOT 80            // N = 80
#define FD   640
#define HIDN 4096
#define DNIN 465
#define LRDNI 1e-3f

// ---------------- init: supp = mean(feat_support, axis=1); qbuf = feat_query ----
__global__ void k_init(const float* __restrict__ fs, const float* __restrict__ fq,
                       float* __restrict__ supp, float* __restrict__ qbuf) {
    int idx = blockIdx.x * 256 + threadIdx.x;
    if (idx < NCLS * FD) {
        int c = idx / FD, d = idx % FD;
        float s = 0.f;
        #pragma unroll
        for (int t = 0; t < 5; t++) s += fs[(c * 5 + t) * FD + d];
        supp[idx] = s * 0.2f;
    }
    if (idx < NQRY * FD) qbuf[idx] = fq[idx];
}

// ---------------- row-normalize concat([supp,qbuf]) -> f (80x640), nrm (80) ----
__global__ void k_norm(const float* __restrict__ supp, const float* __restrict__ qbuf,
                       float* __restrict__ f, float* __restrict__ nrm) {
    int r = blockIdx.x;                 // 0..79
    const float* src = (r < NCLS) ? (supp + r * FD) : (qbuf + (r - NCLS) * FD);
    int t = threadIdx.x;                // 64 threads
    float v[10]; float ss = 0.f;
    #pragma unroll
    for (int u = 0; u < 10; u++) { v[u] = src[t + 64 * u]; ss += v[u] * v[u]; }
    #pragma unroll
    for (int o = 32; o > 0; o >>= 1) ss += __shfl_xor(ss, o, 64);
    float n = fmaxf(sqrtf(ss), 1e-12f);
    if (t == 0) nrm[r] = n;
    float inv = 1.0f / n;
    #pragma unroll
    for (int u = 0; u < 10; u++) f[r * FD + t + 64 * u] = v[u] * inv;
}

// ---------------- S = f @ f^T  (80x80) ----------------
__global__ void k_sim(const float* __restrict__ f, float* __restrict__ S) {
    __shared__ float fi[FD];
    int i = blockIdx.x;
    for (int u = threadIdx.x; u < FD; u += 128) fi[u] = f[i * FD + u];
    __syncthreads();
    int j = threadIdx.x;
    if (j < NTOT) {
        const float* fj = f + j * FD;
        float acc = 0.f;
        for (int k = 0; k < FD; k += 4) {
            float4 a = *(const float4*)(fi + k);
            float4 b = *(const float4*)(fj + k);
            acc += a.x * b.x + a.y * b.y + a.z * b.z + a.w * b.w;
        }
        S[i * NTOT + j] = acc;
    }
}

// ---------------- stable-descending rank -> perm (80x81) ----------------
__global__ void k_rank(const float* __restrict__ S, int* __restrict__ perm) {
    __shared__ float row[NTOT];
    int i = blockIdx.x;
    int t = threadIdx.x;                // 128 threads
    if (t < NTOT) row[t] = S[i * NTOT + t];
    __syncthreads();
    if (t == 0) perm[i * 81] = i;
    if (t < NCLS) {
        float v = row[t]; int rank = 0;
        for (int k = 0; k < NCLS; k++) {
            float w = row[k];
            if (w > v || (w == v && k < t)) rank++;
        }
        perm[i * 81 + 1 + rank] = t;
    } else if (t < NTOT) {
        int j = t - NCLS; float v = row[t]; int rank = 0;
        for (int k = NCLS; k < NTOT; k++) {
            float w = row[k];
            if (w > v || (w == v && (k - NCLS) < j)) rank++;
        }
        perm[i * 81 + 6 + rank] = t;    // t = query idx + 5 already
    }
}

// m -> (a,b): masked entries of 81x81, row-major; a in 0..5, b in a+1..80
__device__ __forceinline__ void mask_ab(int m, int& a, int& b) {
    int start = 0, len = 80, aa = 0;
    while (m >= start + len) { start += len; len--; aa++; }
    a = aa; b = aa + 1 + (m - start);
}

// ---------------- gather X[i][m] = S[p[a]][p[b]] ----------------
__global__ void k_gather(const float* __restrict__ S, const int* __restrict__ perm,
                         float* __restrict__ X) {
    __shared__ int p[81];
    int i = blockIdx.x;
    if (threadIdx.x < 81) p[threadIdx.x] = perm[i * 81 + threadIdx.x];
    __syncthreads();
    int m = threadIdx.x;                // 512 threads
    if (m < DNIN) {
        int a, b; mask_ab(m, a, b);
        X[i * DNIN + m] = S[p[a] * NTOT + p[b]];
    }
}

// ---------------- tiled fp32 GEMM: C[M,N] = act(A[M,K] @ B[N,K]^T + bias) ------
#define BM 16
#define BN 64
#define BK 32
__global__ void k_gemm_nt(const float* __restrict__ A, const float* __restrict__ B,
                          const float* __restrict__ bias, float* __restrict__ C,
                          int Mm, int Nn, int Kk, int relu) {
    __shared__ float As[BM][BK];
    __shared__ float Bs[BK][BN + 1];
    int bn = blockIdx.x * BN;
    int bm = blockIdx.y * BM;
    int tid = threadIdx.x;              // 256
    int tx = tid & 63;                  // col in tile
    int ty = tid >> 6;                  // 0..3 row group
    float acc[4] = {0.f, 0.f, 0.f, 0.f};
    for (int k0 = 0; k0 < Kk; k0 += BK) {
        for (int u = tid; u < BM * BK; u += 256) {
            int r = u / BK, c = u % BK;
            int gr = bm + r, gc = k0 + c;
            As[r][c] = (gr < Mm && gc < Kk) ? A[gr * Kk + gc] : 0.f;
        }
        for (int u = tid; u < BN * BK; u += 256) {
            int r = u / BK, c = u % BK; // r = col within tile, c = k
            int gh = bn + r, gc = k0 + c;
            Bs[c][r] = (gh < Nn && gc < Kk) ? B[gh * Kk + gc] : 0.f;
        }
        __syncthreads();
        #pragma unroll
        for (int kk = 0; kk < BK; kk++) {
            float bv = Bs[kk][tx];
            acc[0] += As[ty][kk]      * bv;
            acc[1] += As[ty + 4][kk]  * bv;
            acc[2] += As[ty + 8][kk]  * bv;
            acc[3] += As[ty + 12][kk] * bv;
        }
        __syncthreads();
    }
    int col = bn + tx;
    if (col < Nn) {
        float bb = bias[col];
        #pragma unroll
        for (int q = 0; q < 4; q++) {
            int row = bm + ty + q * 4;
            if (row < Mm) {
                float v = acc[q] + bb;
                if (relu) v = fmaxf(v, 0.f);
                C[row * Nn + col] = v;
            }
        }
    }
}

// ---------------- skinny GEMM for layer3: C[80,465] = A[80,4096]@B[465,4096]^T + b
__global__ void k_gemm3(const float* __restrict__ A, const float* __restrict__ B,
                        const float* __restrict__ bias, float* __restrict__ C) {
    int i0 = blockIdx.y * 4;            // rows (80/4 = 20)
    int h0 = blockIdx.x * 4;            // cols (ceil(465/4) = 117)
    int t = threadIdx.x;                // 256
    float acc[4][4] = {};
    for (int k = t; k < HIDN; k += 256) {
        float a[4], b[4];
        #pragma unroll
        for (int u = 0; u < 4; u++) a[u] = A[(i0 + u) * HIDN + k];
        #pragma unroll
        for (int v = 0; v < 4; v++) b[v] = (h0 + v < DNIN) ? B[(h0 + v) * HIDN + k] : 0.f;
        #pragma unroll
        for (int u = 0; u < 4; u++)
            #pragma unroll
            for (int v = 0; v < 4; v++) acc[u][v] += a[u] * b[v];
    }
    #pragma unroll
    for (int o = 32; o > 0; o >>= 1)
        #pragma unroll
        for (int u = 0; u < 4; u++)
            #pragma unroll
            for (int v = 0; v < 4; v++) acc[u][v] += __shfl_xor(acc[u][v], o, 64);
    __shared__ float red[4][4][4];      // [wave][u][v]
    int wave = t >> 6;
    if ((t & 63) == 0)
        for (int u = 0; u < 4; u++)
            for (int v = 0; v < 4; v++) red[wave][u][v] = acc[u][v];
    __syncthreads();
    if (t < 16) {
        int u = t >> 2, v = t & 3;
        int col = h0 + v;
        if (col < DNIN) {
            float s = red[0][u][v] + red[1][u][v] + red[2][u][v] + red[3][u][v];
            C[(i0 + u) * DNIN + col] = s + bias[col];
        }
    }
}

// ---------------- zero ----------------
__global__ void k_zero(float* __restrict__ p, int n) {
    int i = blockIdx.x * 256 + threadIdx.x;
    if (i < n) p[i] = 0.f;
}

// ---------------- scatter-add VJP of the gather ----------------
__global__ void k_scatter(const float* __restrict__ G, const int* __restrict__ perm,
                          float* __restrict__ Gs) {
    __shared__ int p[81];
    int i = blockIdx.x;
    if (threadIdx.x < 81) p[threadIdx.x] = perm[i * 81 + threadIdx.x];
    __syncthreads();
    int m = threadIdx.x;                // 512 threads
    if (m < DNIN) {
        int a, b; mask_ab(m, a, b);
        atomicAdd(&Gs[p[a] * NTOT + p[b]], G[i * DNIN + m]);
    }
}

// ---- dfeat = (Gs+Gs^T) @ f ; dx = (dfeat - (dfeat.f) f)/n ; target -= LR*dx ----
__global__ void k_bwd(const float* __restrict__ Gs, const float* __restrict__ f,
                      const float* __restrict__ nrm, float* __restrict__ target,
                      int row0) {
    int r = row0 + blockIdx.x;
    __shared__ float cj[NTOT];
    __shared__ float red[2];
    int t = threadIdx.x;                // 128 threads, 5 elems each
    if (t < NTOT) cj[t] = Gs[r * NTOT + t] + Gs[t * NTOT + r];
    __syncthreads();
    float df[5] = {0.f, 0.f, 0.f, 0.f, 0.f};
    for (int j = 0; j < NTOT; j++) {
        float c = cj[j];
        const float* fj = f + j * FD;
        #pragma unroll
        for (int u = 0; u < 5; u++) df[u] += c * fj[t + 128 * u];
    }
    const float* fr = f + r * FD;
    float frv[5]; float partial = 0.f;
    #pragma unroll
    for (int u = 0; u < 5; u++) { frv[u] = fr[t + 128 * u]; partial += df[u] * frv[u]; }
    #pragma unroll
    for (int o = 32; o > 0; o >>= 1) partial += __shfl_xor(partial, o, 64);
    if ((t & 63) == 0) red[t >> 6] = partial;
    __syncthreads();
    float dot = red[0] + red[1];
    float invn = 1.0f / nrm[r];
    float* dst = target + blockIdx.x * FD;
    #pragma unroll
    for (int u = 0; u < 5; u++) {
        float dx = (df[u] - dot * frv[u]) * invn;
        dst[t + 128 * u] -= LRDNI * dx;
    }
}

// ---------------- output: out[j*5+i] = S[i][5+j] * scale ----------------
__global__ void k_out(const float* __restrict__ S, const float* __restrict__ scale,
                      float* __restrict__ out) {
    int idx = blockIdx.x * 128 + threadIdx.x;
    if (idx < NQRY * NCLS) {
        int j = idx / NCLS, i = idx % NCLS;
        out[idx] = S[i * NTOT + (NCLS + j)] * scale[0];
    }
}

extern "C" void kernel_launch(void* const* d_in, const int* in_sizes, int n_in,
                              void* d_out, int out_size, void* d_ws, size_t ws_size,
                              hipStream_t stream) {
    const float* fs    = (const float*)d_in[0];
    const float* fq    = (const float*)d_in[1];
    const float* scale = (const float*)d_in[2];
    const float* W[12];
    for (int i = 0; i < 12; i++) W[i] = (const float*)d_in[3 + i];
    // W[0..5] = ds_{W1,b1,W2,b2,W3,b3}; W[6..11] = dq_*

    float* ws   = (float*)d_ws;
    float* supp = ws;                   // 3200
    float* qbuf = supp + 3200;          // 48000
    float* f    = qbuf + 48000;         // 51200
    float* nrm  = f + 51200;            // 80
    float* S    = nrm + 80;             // 6400
    int*   perm = (int*)(S + 6400);     // 6480 ints
    float* X    = (float*)(perm + 6480);// 37200
    float* H1   = X + 37200;            // 327680
    float* H2   = H1 + 327680;          // 327680
    float* G    = H2 + 327680;          // 37200
    float* Gs   = G + 37200;            // 6400

    k_init<<<188, 256, 0, stream>>>(fs, fq, supp, qbuf);

    for (int step = 0; step < 3; step++) {
        for (int half = 0; half < 2; half++) {
            const float* const* w = (half == 0) ? W : (W + 6);
            k_norm<<<80, 64, 0, stream>>>(supp, qbuf, f, nrm);
            k_sim<<<80, 128, 0, stream>>>(f, S);
            k_rank<<<80, 128, 0, stream>>>(S, perm);
            k_gather<<<80, 512, 0, stream>>>(S, perm, X);
            k_gemm_nt<<<dim3(64, 5), 256, 0, stream>>>(X,  w[0], w[1], H1, NTOT, HIDN, DNIN, 1);
            k_gemm_nt<<<dim3(64, 5), 256, 0, stream>>>(H1, w[2], w[3], H2, NTOT, HIDN, HIDN, 1);
            k_gemm3<<<dim3(117, 20), 256, 0, stream>>>(H2, w[4], w[5], G);
            k_zero<<<25, 256, 0, stream>>>(Gs, NTOT * NTOT);
            k_scatter<<<80, 512, 0, stream>>>(G, perm, Gs);
            if (half == 0) k_bwd<<<5, 128, 0, stream>>>(Gs, f, nrm, supp, 0);
            else           k_bwd<<<75, 128, 0, stream>>>(Gs, f, nrm, qbuf, NCLS);
        }
    }
    k_norm<<<80, 64, 0, stream>>>(supp, qbuf, f, nrm);
    k_sim<<<80, 128, 0, stream>>>(f, S);
    k_out<<<3, 128, 0, stream>>>(S, scale, (float*)d_out);
}

// Round 2
// 834.712 us; speedup vs baseline: 4.9532x; 4.9532x over previous
//
#include <hip/hip_runtime.h>

#define NCLS 5
#define NQRY 75
#define NTOT 80            // N = 80
#define FD   640
#define HIDN 4096
#define DNIN 465
#define KPAD 512           // DNIN padded to 512 for MFMA K
#define NPAD 512           // DNIN padded for GEMM3 N
#define LRDNI 1e-3f

typedef short  v8s __attribute__((ext_vector_type(8)));
typedef float  v4f __attribute__((ext_vector_type(4)));

__device__ __forceinline__ ushort f2bf(float x) {
    uint u = __float_as_uint(x);
    u = (u + 0x7FFFu + ((u >> 16) & 1u)) >> 16;
    return (ushort)u;
}
__device__ __forceinline__ uint pk2(float a, float b) {
    return (uint)f2bf(a) | ((uint)f2bf(b) << 16);
}

// ---------------- init: supp = mean(feat_support, axis=1); qbuf = feat_query ----
__global__ void k_init(const float* __restrict__ fs, const float* __restrict__ fq,
                       float* __restrict__ supp, float* __restrict__ qbuf) {
    int idx = blockIdx.x * 256 + threadIdx.x;
    if (idx < NCLS * FD) {
        int c = idx / FD, d = idx % FD;
        float s = 0.f;
        #pragma unroll
        for (int t = 0; t < 5; t++) s += fs[(c * 5 + t) * FD + d];
        supp[idx] = s * 0.2f;
    }
    if (idx < NQRY * FD) qbuf[idx] = fq[idx];
}

// ---------------- weight converts (once per launch) ----------------
// W1 [4096,465] fp32 -> [4096,512] bf16 zero-padded K
__global__ void k_cvtW1(const float* __restrict__ W, ushort* __restrict__ Wb) {
    int idx = blockIdx.x * 256 + threadIdx.x;      // 4096*512
    int r = idx >> 9, c = idx & 511;
    Wb[idx] = (c < DNIN) ? f2bf(W[r * DNIN + c]) : (ushort)0;
}
// W3 [465,4096] fp32 -> [512,4096] bf16 zero-padded rows
__global__ void k_cvtW3(const float* __restrict__ W, ushort* __restrict__ Wb) {
    int idx = blockIdx.x * 256 + threadIdx.x;      // 512*4096
    int r = idx >> 12;
    Wb[idx] = (r < DNIN) ? f2bf(W[idx]) : (ushort)0;
}

// ---------------- row-normalize concat([supp,qbuf]) -> f (80x640), nrm (80) ----
__global__ void k_norm(const float* __restrict__ supp, const float* __restrict__ qbuf,
                       float* __restrict__ f, float* __restrict__ nrm) {
    int r = blockIdx.x;                 // 0..79
    const float* src = (r < NCLS) ? (supp + r * FD) : (qbuf + (r - NCLS) * FD);
    int t = threadIdx.x;                // 64 threads
    float v[10]; float ss = 0.f;
    #pragma unroll
    for (int u = 0; u < 10; u++) { v[u] = src[t + 64 * u]; ss += v[u] * v[u]; }
    #pragma unroll
    for (int o = 32; o > 0; o >>= 1) ss += __shfl_xor(ss, o, 64);
    float n = fmaxf(sqrtf(ss), 1e-12f);
    if (t == 0) nrm[r] = n;
    float inv = 1.0f / n;
    #pragma unroll
    for (int u = 0; u < 10; u++) f[r * FD + t + 64 * u] = v[u] * inv;
}

// ---------------- S = f @ f^T (80x80) + stable-descending rank -> perm --------
__global__ void k_simrank(const float* __restrict__ f, float* __restrict__ S,
                          int* __restrict__ perm) {
    __shared__ float fi[FD];
    __shared__ float row[NTOT];
    int i = blockIdx.x;
    int t = threadIdx.x;                // 128
    for (int u = t; u < FD; u += 128) fi[u] = f[i * FD + u];
    __syncthreads();
    if (t < NTOT) {
        const float* fj = f + t * FD;
        float acc = 0.f;
        for (int k = 0; k < FD; k += 4) {
            float4 a = *(const float4*)(fi + k);
            float4 b = *(const float4*)(fj + k);
            acc += a.x * b.x + a.y * b.y + a.z * b.z + a.w * b.w;
        }
        row[t] = acc;
        S[i * NTOT + t] = acc;
    }
    __syncthreads();
    if (t == 0) perm[i * 81] = i;
    if (t < NCLS) {
        float v = row[t]; int rank = 0;
        for (int k = 0; k < NCLS; k++) {
            float w = row[k];
            if (w > v || (w == v && k < t)) rank++;
        }
        perm[i * 81 + 1 + rank] = t;
    } else if (t < NTOT) {
        int j = t - NCLS; float v = row[t]; int rank = 0;
        for (int k = NCLS; k < NTOT; k++) {
            float w = row[k];
            if (w > v || (w == v && (k - NCLS) < j)) rank++;
        }
        perm[i * 81 + 6 + rank] = t;
    }
}

// m -> (a,b): masked entries of 81x81, row-major; a in 0..5, b in a+1..80
__device__ __forceinline__ void mask_ab(int m, int& a, int& b) {
    int start = 0, len = 80, aa = 0;
    while (m >= start + len) { start += len; len--; aa++; }
    a = aa; b = aa + 1 + (m - start);
}

// ---------------- gather Xb[i][m] = bf16(S[p[a]][p[b]]) + zero Gs ----------------
__global__ void k_gather(const float* __restrict__ S, const int* __restrict__ perm,
                         ushort* __restrict__ Xb, float* __restrict__ Gs) {
    __shared__ int p[81];
    int i = blockIdx.x;
    int t = threadIdx.x;                // 512
    if (t < 81) p[t] = perm[i * 81 + t];
    if (t < NTOT) Gs[i * NTOT + t] = 0.f;
    __syncthreads();
    if (t < DNIN) {
        int a, b; mask_ab(t, a, b);
        Xb[i * KPAD + t] = f2bf(S[p[a] * NTOT + p[b]]);
    } else if (t < KPAD) {
        Xb[i * KPAD + t] = 0;
    }
}

// ---------------- bf16 MFMA GEMM: C[80,N] (+)= A[80,K] @ B[N,K]^T ----------------
// A bf16 row-major [80][lda]; B bf16 [N][ldb] (or fp32 converted inline if BF32).
// NT = N-tiles (of 16) per wave; block = 4 waves side by side -> NB = NT*64 cols.
// grid.x = N / NB ; grid.y = K-split (each handles kiters*64 of K).
// EP==0: write fp32 partials to C + ks*80*ldc.  EP==1: bias+relu -> bf16 C.
template<int NT, bool BF32, int EP>
__global__ __launch_bounds__(256) void k_gemm(
        const ushort* __restrict__ A, int lda,
        const void* __restrict__ Bv, int ldb,
        const float* __restrict__ bias,
        void* __restrict__ Cv, int ldc, int kiters) {
    const int NB = NT * 64;
    __shared__ ushort As[80][72];       // +8 pad: 2-way bank alias only (free)
    __shared__ ushort Bs[NB][72];
    int tid = threadIdx.x;
    int w = tid >> 6, lane = tid & 63, l16 = lane & 15, quad = lane >> 4;
    int n00 = blockIdx.x * NB;
    int ks = blockIdx.y;
    int kc0 = ks * kiters * 64;

    v4f acc[5][NT];
    #pragma unroll
    for (int mt = 0; mt < 5; mt++)
        #pragma unroll
        for (int nt = 0; nt < NT; nt++) acc[mt][nt] = (v4f){0.f, 0.f, 0.f, 0.f};

    for (int it = 0; it < kiters; it++) {
        int k0 = kc0 + it * 64;
        // stage A: 80 rows x 64 bf16 = 640 octs of 8 elems
        for (int o = tid; o < 640; o += 256) {
            int r = o >> 3, c8 = o & 7;
            *(uint4*)&As[r][c8 * 8] = *(const uint4*)(A + r * lda + k0 + c8 * 8);
        }
        // stage B: NB rows x 64
        if (BF32) {
            const float* B = (const float*)Bv;
            #pragma unroll
            for (int o = tid; o < NB * 8; o += 256) {
                int r = o >> 3, c8 = o & 7;
                const float* p = B + (size_t)(n00 + r) * ldb + k0 + c8 * 8;
                float4 f0 = *(const float4*)p;
                float4 f1 = *(const float4*)(p + 4);
                uint4 q;
                q.x = pk2(f0.x, f0.y); q.y = pk2(f0.z, f0.w);
                q.z = pk2(f1.x, f1.y); q.w = pk2(f1.z, f1.w);
                *(uint4*)&Bs[r][c8 * 8] = q;
            }
        } else {
            const ushort* B = (const ushort*)Bv;
            #pragma unroll
            for (int o = tid; o < NB * 8; o += 256) {
                int r = o >> 3, c8 = o & 7;
                *(uint4*)&Bs[r][c8 * 8] = *(const uint4*)(B + (size_t)(n00 + r) * ldb + k0 + c8 * 8);
            }
        }
        __syncthreads();
        #pragma unroll
        for (int kb = 0; kb < 2; kb++) {
            int ko = kb * 32 + quad * 8;
            v8s bf[NT];
            #pragma unroll
            for (int nt = 0; nt < NT; nt++)
                bf[nt] = *(const v8s*)&Bs[w * NT * 16 + nt * 16 + l16][ko];
            #pragma unroll
            for (int mt = 0; mt < 5; mt++) {
                v8s af = *(const v8s*)&As[mt * 16 + l16][ko];
                #pragma unroll
                for (int nt = 0; nt < NT; nt++)
                    acc[mt][nt] = __builtin_amdgcn_mfma_f32_16x16x32_bf16(af, bf[nt], acc[mt][nt], 0, 0, 0);
            }
        }
        __syncthreads();
    }
    // epilogue: C row = mt*16 + quad*4 + r ; col = n00 + w*NT*16 + nt*16 + l16
    #pragma unroll
    for (int nt = 0; nt < NT; nt++) {
        int col = n00 + w * NT * 16 + nt * 16 + l16;
        if (EP == 1) {
            float bb = bias[col];
            ushort* C = (ushort*)Cv;
            #pragma unroll
            for (int mt = 0; mt < 5; mt++)
                #pragma unroll
                for (int r = 0; r < 4; r++) {
                    int row = mt * 16 + quad * 4 + r;
                    float v = acc[mt][nt][r] + bb;
                    C[row * ldc + col] = f2bf(fmaxf(v, 0.f));
                }
        } else {
            float* C = (float*)Cv + (size_t)ks * 80 * ldc;
            #pragma unroll
            for (int mt = 0; mt < 5; mt++)
                #pragma unroll
                for (int r = 0; r < 4; r++) {
                    int row = mt * 16 + quad * 4 + r;
                    C[row * ldc + col] = acc[mt][nt][r];
                }
        }
    }
}

// ---------------- H2b = bf16(relu(sum_ks P2 + b2)) ----------------
__global__ void k_ep2(const float* __restrict__ P2, const float* __restrict__ b2,
                      ushort* __restrict__ H2b) {
    int idx = blockIdx.x * 256 + threadIdx.x;      // 80*4096
    int n = idx & 4095;
    float s = b2[n];
    #pragma unroll
    for (int ks = 0; ks < 8; ks++) s += P2[ks * (80 * 4096) + idx];
    H2b[idx] = f2bf(fmaxf(s, 0.f));
}

// ---------------- scatter-add VJP of the gather (sums P3 partials + b3) --------
__global__ void k_scatter(const float* __restrict__ P3, const float* __restrict__ b3,
                          const int* __restrict__ perm, float* __restrict__ Gs) {
    __shared__ int p[81];
    int i = blockIdx.x;
    int t = threadIdx.x;                // 512
    if (t < 81) p[t] = perm[i * 81 + t];
    __syncthreads();
    if (t < DNIN) {
        float g = b3[t];
        #pragma unroll
        for (int ks = 0; ks < 8; ks++) g += P3[ks * (80 * NPAD) + i * NPAD + t];
        int a, b; mask_ab(t, a, b);
        atomicAdd(&Gs[p[a] * NTOT + p[b]], g);
    }
}

// ---- dfeat = (Gs+Gs^T) @ f ; dx = (dfeat - (dfeat.f) f)/n ; target -= LR*dx ----
__global__ void k_bwd(const float* __restrict__ Gs, const float* __restrict__ f,
                      const float* __restrict__ nrm, float* __restrict__ target,
                      int row0) {
    int r = row0 + blockIdx.x;
    __shared__ float cj[NTOT];
    __shared__ float red[2];
    int t = threadIdx.x;                // 128 threads, 5 elems each
    if (t < NTOT) cj[t] = Gs[r * NTOT + t] + Gs[t * NTOT + r];
    __syncthreads();
    float df[5] = {0.f, 0.f, 0.f, 0.f, 0.f};
    for (int j = 0; j < NTOT; j++) {
        float c = cj[j];
        const float* fj = f + j * FD;
        #pragma unroll
        for (int u = 0; u < 5; u++) df[u] += c * fj[t + 128 * u];
    }
    const float* fr = f + r * FD;
    float frv[5]; float partial = 0.f;
    #pragma unroll
    for (int u = 0; u < 5; u++) { frv[u] = fr[t + 128 * u]; partial += df[u] * frv[u]; }
    #pragma unroll
    for (int o = 32; o > 0; o >>= 1) partial += __shfl_xor(partial, o, 64);
    if ((t & 63) == 0) red[t >> 6] = partial;
    __syncthreads();
    float dot = red[0] + red[1];
    float invn = 1.0f / nrm[r];
    float* dst = target + blockIdx.x * FD;
    #pragma unroll
    for (int u = 0; u < 5; u++) {
        float dx = (df[u] - dot * frv[u]) * invn;
        dst[t + 128 * u] -= LRDNI * dx;
    }
}

// ---------------- output: out[j*5+i] = S[i][5+j] * scale ----------------
__global__ void k_out(const float* __restrict__ S, const float* __restrict__ scale,
                      float* __restrict__ out) {
    int idx = blockIdx.x * 128 + threadIdx.x;
    if (idx < NQRY * NCLS) {
        int j = idx / NCLS, i = idx % NCLS;
        out[idx] = S[i * NTOT + (NCLS + j)] * scale[0];
    }
}

extern "C" void kernel_launch(void* const* d_in, const int* in_sizes, int n_in,
                              void* d_out, int out_size, void* d_ws, size_t ws_size,
                              hipStream_t stream) {
    const float* fs    = (const float*)d_in[0];
    const float* fq    = (const float*)d_in[1];
    const float* scale = (const float*)d_in[2];
    const float* W[12];
    for (int i = 0; i < 12; i++) W[i] = (const float*)d_in[3 + i];
    // W[0..5] = ds_{W1,b1,W2,b2,W3,b3}; W[6..11] = dq_*

    float* base = (float*)d_ws;
    float* supp = base;                     // 3200
    float* qbuf = supp + 3200;              // 48000
    float* f    = qbuf + 48000;             // 51200
    float* nrm  = f + 51200;                // 96 (pad)
    float* S    = nrm + 96;                 // 6400
    int*   perm = (int*)(S + 6400);         // 6480 -> pad 6496
    float* P2   = (float*)(perm + 6496);    // 8*80*4096 = 2621440
    float* P3   = P2 + 2621440;             // 8*80*512  = 327680
    float* Gs   = P3 + 327680;              // 6400
    ushort* Xb  = (ushort*)(Gs + 6400);     // 80*512   = 40960 us -> 20480 f
    ushort* H1b = Xb + 40960;               // 80*4096  = 327680 us
    ushort* H2b = H1b + 327680;             // 327680 us
    ushort* W1b_ds = H2b + 327680;          // 4096*512 = 2097152 us
    ushort* W1b_dq = W1b_ds + 2097152;
    ushort* W3b_ds = W1b_dq + 2097152;      // 512*4096 = 2097152 us
    ushort* W3b_dq = W3b_ds + 2097152;

    k_cvtW1<<<8192, 256, 0, stream>>>(W[0],  W1b_ds);
    k_cvtW1<<<8192, 256, 0, stream>>>(W[6],  W1b_dq);
    k_cvtW3<<<8192, 256, 0, stream>>>(W[4],  W3b_ds);
    k_cvtW3<<<8192, 256, 0, stream>>>(W[10], W3b_dq);
    k_init<<<188, 256, 0, stream>>>(fs, fq, supp, qbuf);

    for (int step = 0; step < 3; step++) {
        for (int half = 0; half < 2; half++) {
            const float* const* w = (half == 0) ? W : (W + 6);
            const ushort* W1b = (half == 0) ? W1b_ds : W1b_dq;
            const ushort* W3b = (half == 0) ? W3b_ds : W3b_dq;
            k_norm<<<80, 64, 0, stream>>>(supp, qbuf, f, nrm);
            k_simrank<<<80, 128, 0, stream>>>(f, S, perm);
            k_gather<<<80, 512, 0, stream>>>(S, perm, Xb, Gs);
            // L1: H1b = relu(Xb @ W1b^T + b1)   M=80 N=4096 K=512 (full-K)
            k_gemm<1, false, 1><<<dim3(64, 1), 256, 0, stream>>>(
                Xb, KPAD, W1b, KPAD, w[1], H1b, HIDN, 8);
            // L2 partials: P2[ks] = H1b @ W2^T (fp32 W2 converted inline), K split 8
            k_gemm<2, true, 0><<<dim3(32, 8), 256, 0, stream>>>(
                H1b, HIDN, w[2], HIDN, nullptr, P2, HIDN, 8);
            k_ep2<<<1280, 256, 0, stream>>>(P2, w[3], H2b);
            // L3 partials: P3[ks] = H2b @ W3b^T  N=512(padded) K=4096 split 8
            k_gemm<1, false, 0><<<dim3(8, 8), 256, 0, stream>>>(
                H2b, HIDN, W3b, HIDN, nullptr, P3, NPAD, 8);
            k_scatter<<<80, 512, 0, stream>>>(P3, w[5], perm, Gs);
            if (half == 0) k_bwd<<<5, 128, 0, stream>>>(Gs, f, nrm, supp, 0);
            else           k_bwd<<<75, 128, 0, stream>>>(Gs, f, nrm, qbuf, NCLS);
        }
    }
    k_norm<<<80, 64, 0, stream>>>(supp, qbuf, f, nrm);
    k_simrank<<<80, 128, 0, stream>>>(f, S, perm);
    k_out<<<3, 128, 0, stream>>>(S, scale, (float*)d_out);
}

// Round 3
// 654.634 us; speedup vs baseline: 6.3157x; 1.2751x over previous
//
#include <hip/hip_runtime.h>

#define NCLS 5
#define NQRY 75
#define NTOT 80            // N = 80
#define FD   640
#define HIDN 4096
#define DNIN 465
#define KPAD 512           // DNIN padded to 512 for MFMA K
#define NPAD 512           // DNIN padded for GEMM3 N
#define LRDNI 1e-3f

#define KS1 4              // K-splits layer1 (K=512)
#define KS2 16             // K-splits layer2 (K=4096)
#define KS3 32             // K-splits layer3 (K=4096)

typedef short  v8s __attribute__((ext_vector_type(8)));
typedef float  v4f __attribute__((ext_vector_type(4)));

__device__ __forceinline__ ushort f2bf(float x) {
    uint u = __float_as_uint(x);
    u = (u + 0x7FFFu + ((u >> 16) & 1u)) >> 16;
    return (ushort)u;
}
__device__ __forceinline__ uint pk2(float a, float b) {
    return (uint)f2bf(a) | ((uint)f2bf(b) << 16);
}

// ---------------- init: supp = mean(feat_support, axis=1); qbuf = feat_query ----
__global__ void k_init(const float* __restrict__ fs, const float* __restrict__ fq,
                       float* __restrict__ supp, float* __restrict__ qbuf) {
    int idx = blockIdx.x * 256 + threadIdx.x;
    if (idx < NCLS * FD) {
        int c = idx / FD, d = idx % FD;
        float s = 0.f;
        #pragma unroll
        for (int t = 0; t < 5; t++) s += fs[(c * 5 + t) * FD + d];
        supp[idx] = s * 0.2f;
    }
    if (idx < NQRY * FD) qbuf[idx] = fq[idx];
}

// ---------------- weight converts (once per launch) ----------------
// W1 [4096,465] fp32 -> [4096,512] bf16 zero-padded K
__global__ void k_cvtW1(const float* __restrict__ W, ushort* __restrict__ Wb) {
    int idx = blockIdx.x * 256 + threadIdx.x;      // 4096*512
    int r = idx >> 9, c = idx & 511;
    Wb[idx] = (c < DNIN) ? f2bf(W[r * DNIN + c]) : (ushort)0;
}
// W3 [465,4096] fp32 -> [512,4096] bf16 zero-padded rows
__global__ void k_cvtW3(const float* __restrict__ W, ushort* __restrict__ Wb) {
    int idx = blockIdx.x * 256 + threadIdx.x;      // 512*4096
    int r = idx >> 12;
    Wb[idx] = (r < DNIN) ? f2bf(W[idx]) : (ushort)0;
}

__device__ __forceinline__ const float* rowptr(const float* supp, const float* qbuf, int r) {
    return (r < NCLS) ? (supp + r * FD) : (qbuf + (r - NCLS) * FD);
}

// ---- fused: norms + S = fn@fn^T + f (normalized) + stable rank -> perm --------
// FIN variant: only writes out[j*5+i] = S[i][5+j]*scale  (grid = 5 blocks)
template<bool FIN>
__global__ void k_simrank(const float* __restrict__ supp, const float* __restrict__ qbuf,
                          float* __restrict__ f, float* __restrict__ nrm,
                          float* __restrict__ S, int* __restrict__ perm,
                          const float* __restrict__ scale, float* __restrict__ out) {
    __shared__ float fi[FD];
    __shared__ float row[NTOT];
    __shared__ float ssh[NTOT];
    int i = blockIdx.x;
    int t = threadIdx.x;                // 128
    const float* ri = rowptr(supp, qbuf, i);
    for (int u = t; u < FD; u += 128) fi[u] = ri[u];
    __syncthreads();
    float dot = 0.f;
    if (t < NTOT) {
        const float* rj = rowptr(supp, qbuf, t);
        float ss = 0.f;
        for (int k = 0; k < FD; k += 4) {
            float4 a = *(const float4*)(fi + k);
            float4 b = *(const float4*)(rj + k);
            dot += a.x * b.x + a.y * b.y + a.z * b.z + a.w * b.w;
            ss  += b.x * b.x + b.y * b.y + b.z * b.z + b.w * b.w;
        }
        ssh[t] = ss;
    }
    __syncthreads();
    float ni = fmaxf(sqrtf(ssh[i]), 1e-12f);
    float inv_i = 1.0f / ni;
    if (t < NTOT) {
        float nt = fmaxf(sqrtf(ssh[t]), 1e-12f);
        float val = dot * inv_i / nt;
        if (FIN) {
            if (t >= NCLS) out[(t - NCLS) * NCLS + i] = val * scale[0];
        } else {
            row[t] = val;
            S[i * NTOT + t] = val;
        }
    }
    if (FIN) return;
    __syncthreads();
    for (int u = t; u < FD; u += 128) f[i * FD + u] = fi[u] * inv_i;
    if (t == 0) { nrm[i] = ni; perm[i * 81] = i; }
    if (t < NCLS) {
        float v = row[t]; int rank = 0;
        for (int k = 0; k < NCLS; k++) {
            float w = row[k];
            if (w > v || (w == v && k < t)) rank++;
        }
        perm[i * 81 + 1 + rank] = t;
    } else if (t < NTOT) {
        int j = t - NCLS; float v = row[t]; int rank = 0;
        for (int k = NCLS; k < NTOT; k++) {
            float w = row[k];
            if (w > v || (w == v && (k - NCLS) < j)) rank++;
        }
        perm[i * 81 + 6 + rank] = t;
    }
}

// m -> (a,b): masked entries of 81x81, row-major; a in 0..5, b in a+1..80
__device__ __forceinline__ void mask_ab(int m, int& a, int& b) {
    int start = 0, len = 80, aa = 0;
    while (m >= start + len) { start += len; len--; aa++; }
    a = aa; b = aa + 1 + (m - start);
}

// ---------------- gather Xb[i][m] = bf16(S[p[a]][p[b]]) + zero Gs ----------------
__global__ void k_gather(const float* __restrict__ S, const int* __restrict__ perm,
                         ushort* __restrict__ Xb, float* __restrict__ Gs) {
    __shared__ int p[81];
    int i = blockIdx.x;
    int t = threadIdx.x;                // 512
    if (t < 81) p[t] = perm[i * 81 + t];
    if (t < NTOT) Gs[i * NTOT + t] = 0.f;
    __syncthreads();
    if (t < DNIN) {
        int a, b; mask_ab(t, a, b);
        Xb[i * KPAD + t] = f2bf(S[p[a] * NTOT + p[b]]);
    } else if (t < KPAD) {
        Xb[i * KPAD + t] = 0;
    }
}

// ---------------- bf16 MFMA GEMM partials: P[ks][80][ldc] = A[80,K] @ B[N,K]^T --
// A bf16 row-major; B bf16 [N][ldb] or fp32 converted inline (BF32).
// NT = 16-col tiles per wave; NB = NT*64 cols per block. grid.x = N/NB,
// grid.y = K-split; each split covers kiters*64 of K.
template<int NT, bool BF32>
__global__ __launch_bounds__(256) void k_gemm(
        const ushort* __restrict__ A, int lda,
        const void* __restrict__ Bv, int ldb,
        float* __restrict__ C, int ldc, int kiters) {
    const int NB = NT * 64;
    __shared__ ushort As[80][68];       // stride 34 dwords: 2-way alias only (free)
    __shared__ ushort Bs[NB][68];
    int tid = threadIdx.x;
    int w = tid >> 6, lane = tid & 63, l16 = lane & 15, quad = lane >> 4;
    int n00 = blockIdx.x * NB;
    int ks = blockIdx.y;
    int kc0 = ks * kiters * 64;

    v4f acc[5][NT];
    #pragma unroll
    for (int mt = 0; mt < 5; mt++)
        #pragma unroll
        for (int nt = 0; nt < NT; nt++) acc[mt][nt] = (v4f){0.f, 0.f, 0.f, 0.f};

    for (int it = 0; it < kiters; it++) {
        int k0 = kc0 + it * 64;
        // stage A: 80 rows x 64 bf16
        for (int o = tid; o < 640; o += 256) {
            int r = o >> 3, c8 = o & 7;
            *(uint4*)&As[r][c8 * 8] = *(const uint4*)(A + r * lda + k0 + c8 * 8);
        }
        // stage B: NB rows x 64
        if (BF32) {
            const float* B = (const float*)Bv;
            #pragma unroll
            for (int o = tid; o < NB * 8; o += 256) {
                int r = o >> 3, c8 = o & 7;
                const float* p = B + (size_t)(n00 + r) * ldb + k0 + c8 * 8;
                float4 f0 = *(const float4*)p;
                float4 f1 = *(const float4*)(p + 4);
                uint4 q;
                q.x = pk2(f0.x, f0.y); q.y = pk2(f0.z, f0.w);
                q.z = pk2(f1.x, f1.y); q.w = pk2(f1.z, f1.w);
                *(uint4*)&Bs[r][c8 * 8] = q;
            }
        } else {
            const ushort* B = (const ushort*)Bv;
            #pragma unroll
            for (int o = tid; o < NB * 8; o += 256) {
                int r = o >> 3, c8 = o & 7;
                *(uint4*)&Bs[r][c8 * 8] = *(const uint4*)((const ushort*)B + (size_t)(n00 + r) * ldb + k0 + c8 * 8);
            }
        }
        __syncthreads();
        #pragma unroll
        for (int kb = 0; kb < 2; kb++) {
            int ko = kb * 32 + quad * 8;
            v8s bf[NT];
            #pragma unroll
            for (int nt = 0; nt < NT; nt++)
                bf[nt] = *(const v8s*)&Bs[w * NT * 16 + nt * 16 + l16][ko];
            #pragma unroll
            for (int mt = 0; mt < 5; mt++) {
                v8s af = *(const v8s*)&As[mt * 16 + l16][ko];
                #pragma unroll
                for (int nt = 0; nt < NT; nt++)
                    acc[mt][nt] = __builtin_amdgcn_mfma_f32_16x16x32_bf16(af, bf[nt], acc[mt][nt], 0, 0, 0);
            }
        }
        __syncthreads();
    }
    // write fp32 partials: row = mt*16 + quad*4 + r ; col = n00 + w*NT*16 + nt*16 + l16
    float* Cp = C + (size_t)ks * 80 * ldc;
    #pragma unroll
    for (int nt = 0; nt < NT; nt++) {
        int col = n00 + w * NT * 16 + nt * 16 + l16;
        #pragma unroll
        for (int mt = 0; mt < 5; mt++)
            #pragma unroll
            for (int r = 0; r < 4; r++)
                Cp[(mt * 16 + quad * 4 + r) * ldc + col] = acc[mt][nt][r];
    }
}

// ---------------- H = bf16(relu(sum_ks P + bias))  (80 x 4096) ----------------
template<int NS>
__global__ void k_ep(const float* __restrict__ P, const float* __restrict__ bias,
                     ushort* __restrict__ H) {
    int idx = blockIdx.x * 256 + threadIdx.x;      // 80*4096
    float s = bias[idx & 4095];
    #pragma unroll
    for (int ks = 0; ks < NS; ks++) s += P[ks * (80 * HIDN) + idx];
    H[idx] = f2bf(fmaxf(s, 0.f));
}

// ---------------- scatter-add VJP of the gather (sums P3 partials + b3) --------
__global__ void k_scatter(const float* __restrict__ P3, const float* __restrict__ b3,
                          const int* __restrict__ perm, float* __restrict__ Gs) {
    __shared__ int p[81];
    int i = blockIdx.x;
    int t = threadIdx.x;                // 512
    if (t < 81) p[t] = perm[i * 81 + t];
    __syncthreads();
    if (t < DNIN) {
        float g = b3[t];
        #pragma unroll
        for (int ks = 0; ks < KS3; ks++) g += P3[ks * (80 * NPAD) + i * NPAD + t];
        int a, b; mask_ab(t, a, b);
        atomicAdd(&Gs[p[a] * NTOT + p[b]], g);
    }
}

// ---- dfeat = (Gs+Gs^T) @ f ; dx = (dfeat - (dfeat.f) f)/n ; target -= LR*dx ----
__global__ void k_bwd(const float* __restrict__ Gs, const float* __restrict__ f,
                      const float* __restrict__ nrm, float* __restrict__ target,
                      int row0) {
    int r = row0 + blockIdx.x;
    __shared__ float cj[NTOT];
    __shared__ float red[2];
    int t = threadIdx.x;                // 128 threads, 5 elems each
    if (t < NTOT) cj[t] = Gs[r * NTOT + t] + Gs[t * NTOT + r];
    __syncthreads();
    float df[5] = {0.f, 0.f, 0.f, 0.f, 0.f};
    for (int j = 0; j < NTOT; j++) {
        float c = cj[j];
        const float* fj = f + j * FD;
        #pragma unroll
        for (int u = 0; u < 5; u++) df[u] += c * fj[t + 128 * u];
    }
    const float* fr = f + r * FD;
    float frv[5]; float partial = 0.f;
    #pragma unroll
    for (int u = 0; u < 5; u++) { frv[u] = fr[t + 128 * u]; partial += df[u] * frv[u]; }
    #pragma unroll
    for (int o = 32; o > 0; o >>= 1) partial += __shfl_xor(partial, o, 64);
    if ((t & 63) == 0) red[t >> 6] = partial;
    __syncthreads();
    float dot = red[0] + red[1];
    float invn = 1.0f / nrm[r];
    float* dst = target + blockIdx.x * FD;
    #pragma unroll
    for (int u = 0; u < 5; u++) {
        float dx = (df[u] - dot * frv[u]) * invn;
        dst[t + 128 * u] -= LRDNI * dx;
    }
}

extern "C" void kernel_launch(void* const* d_in, const int* in_sizes, int n_in,
                              void* d_out, int out_size, void* d_ws, size_t ws_size,
                              hipStream_t stream) {
    const float* fs    = (const float*)d_in[0];
    const float* fq    = (const float*)d_in[1];
    const float* scale = (const float*)d_in[2];
    const float* W[12];
    for (int i = 0; i < 12; i++) W[i] = (const float*)d_in[3 + i];
    // W[0..5] = ds_{W1,b1,W2,b2,W3,b3}; W[6..11] = dq_*

    float* base = (float*)d_ws;
    float* supp = base;                     // 3200
    float* qbuf = supp + 3200;              // 48000
    float* f    = qbuf + 48000;             // 51200
    float* nrm  = f + 51200;                // 96 (pad)
    float* S    = nrm + 96;                 // 6400
    int*   perm = (int*)(S + 6400);         // 6480 -> pad 6496
    float* P1   = (float*)(perm + 6496);    // KS1*80*4096 = 1310720
    float* P2   = P1 + (size_t)KS1 * 80 * HIDN;   // KS2*80*4096 = 5242880
    float* P3   = P2 + (size_t)KS2 * 80 * HIDN;   // KS3*80*512  = 1310720
    float* Gs   = P3 + (size_t)KS3 * 80 * NPAD;   // 6400
    ushort* Xb  = (ushort*)(Gs + 6400);     // 80*512
    ushort* H1b = Xb + 80 * KPAD;           // 80*4096
    ushort* H2b = H1b + 80 * HIDN;          // 80*4096
    ushort* W1b_ds = H2b + 80 * HIDN;       // 4096*512
    ushort* W1b_dq = W1b_ds + HIDN * KPAD;
    ushort* W3b_ds = W1b_dq + HIDN * KPAD;  // 512*4096
    ushort* W3b_dq = W3b_ds + NPAD * HIDN;

    k_cvtW1<<<8192, 256, 0, stream>>>(W[0],  W1b_ds);
    k_cvtW1<<<8192, 256, 0, stream>>>(W[6],  W1b_dq);
    k_cvtW3<<<8192, 256, 0, stream>>>(W[4],  W3b_ds);
    k_cvtW3<<<8192, 256, 0, stream>>>(W[10], W3b_dq);
    k_init<<<188, 256, 0, stream>>>(fs, fq, supp, qbuf);

    for (int step = 0; step < 3; step++) {
        for (int half = 0; half < 2; half++) {
            const float* const* w = (half == 0) ? W : (W + 6);
            const ushort* W1b = (half == 0) ? W1b_ds : W1b_dq;
            const ushort* W3b = (half == 0) ? W3b_ds : W3b_dq;
            k_simrank<false><<<80, 128, 0, stream>>>(supp, qbuf, f, nrm, S, perm, nullptr, nullptr);
            k_gather<<<80, 512, 0, stream>>>(S, perm, Xb, Gs);
            // L1 partials: M=80 N=4096 K=512, grid (64, KS1), kiters=2
            k_gemm<1, false><<<dim3(64, KS1), 256, 0, stream>>>(
                Xb, KPAD, W1b, KPAD, P1, HIDN, 2);
            k_ep<KS1><<<1280, 256, 0, stream>>>(P1, w[1], H1b);
            // L2 partials: M=80 N=4096 K=4096 (fp32 W2 inline cvt), grid (32, KS2), kiters=4
            k_gemm<2, true><<<dim3(32, KS2), 256, 0, stream>>>(
                H1b, HIDN, w[2], HIDN, P2, HIDN, 4);
            k_ep<KS2><<<1280, 256, 0, stream>>>(P2, w[3], H2b);
            // L3 partials: M=80 N=512 K=4096, grid (8, KS3), kiters=2
            k_gemm<1, false><<<dim3(8, KS3), 256, 0, stream>>>(
                H2b, HIDN, W3b, HIDN, P3, NPAD, 2);
            k_scatter<<<80, 512, 0, stream>>>(P3, w[5], perm, Gs);
            if (half == 0) k_bwd<<<5, 128, 0, stream>>>(Gs, f, nrm, supp, 0);
            else           k_bwd<<<75, 128, 0, stream>>>(Gs, f, nrm, qbuf, NCLS);
        }
    }
    k_simrank<true><<<5, 128, 0, stream>>>(supp, qbuf, f, nrm, S, perm, scale, (float*)d_out);
}